// Round 3
// baseline (111.462 us; speedup 1.0000x reference)
//
#include <hip/hip_runtime.h>

#define IMGW 28
#define OUTW 26
#define FLAT (OUTW * OUTW)
#define NCLS 10

// lane = image; 8 waves per block split one image-batch's 26 output rows
// {4,4,3,3,3,3,3,3}. wid is readfirstlane'd so all fc_w/conv_w indexing is
// provably wave-uniform -> scalar loads (s_load) feeding v_fmac's SGPR slot.
// 512 blocks x 8 waves = 4096 waves = 4/SIMD (launch_bounds caps VGPR at 128).
__global__ __launch_bounds__(512, 4) void fused_conv_fc_kernel(
    const float* __restrict__ x,       // [B, 784]
    const float* __restrict__ conv_w,  // [3,3]
    const float* __restrict__ fc_w,    // [10, 676]
    const float* __restrict__ fc_b,    // [10]
    float* __restrict__ out)           // [B, 10]
{
    __shared__ float part[7][64][NCLS];   // 17920 B: waves 1..7 partial logits

    const int lane = threadIdx.x & 63;
    const int wid  = __builtin_amdgcn_readfirstlane(threadIdx.x >> 6);
    const int img  = blockIdx.x * 64 + lane;

    const float* ip = x + (size_t)img * (IMGW * IMGW);

    // wave-uniform scalars
    const int nrow = (wid < 2) ? 4 : 3;                  // output rows this wave
    const int s    = (wid < 2) ? 4 * wid : 8 + 3 * (wid - 2);  // first output row

    const float cw0 = conv_w[0], cw1 = conv_w[1], cw2 = conv_w[2];
    const float cw3 = conv_w[3], cw4 = conv_w[4], cw5 = conv_w[5];
    const float cw6 = conv_w[6], cw7 = conv_w[7], cw8 = conv_w[8];

    float acc[NCLS];
#pragma unroll
    for (int c = 0; c < NCLS; ++c) acc[c] = 0.f;

    float r0[IMGW], r1[IMGW], r2[IMGW];

#define LOADROW(BUF, RR) do {                                        \
    const float4* _p = (const float4*)(ip + (size_t)(RR) * IMGW);    \
    _Pragma("unroll")                                                \
    for (int q = 0; q < 7; ++q) *(float4*)(&BUF[4 * q]) = _p[q];     \
} while (0)

    // one output row: conv from A=row R, B=R+1, C=R+2 (registers), then FC
    // with wave-uniform weights (scalar loads -> v_fmac SGPR operand).
#define BODY(A, B, C, R) do {                                         \
    const float* _w = fc_w + (size_t)(R) * OUTW;                      \
    _Pragma("unroll")                                                 \
    for (int cc = 0; cc < OUTW; ++cc) {                               \
        float h = A[cc]     * cw0 + A[cc + 1] * cw1 + A[cc + 2] * cw2 \
                + B[cc]     * cw3 + B[cc + 1] * cw4 + B[cc + 2] * cw5 \
                + C[cc]     * cw6 + C[cc + 1] * cw7 + C[cc + 2] * cw8;\
        h = fmaxf(h, 0.f);                                            \
        _Pragma("unroll")                                             \
        for (int c = 0; c < NCLS; ++c)                                \
            acc[c] = fmaf(h, _w[(size_t)c * FLAT + cc], acc[c]);      \
    }                                                                 \
} while (0)

    LOADROW(r0, s + 0);
    LOADROW(r1, s + 1);
    LOADROW(r2, s + 2);

    BODY(r0, r1, r2, s + 0);
    LOADROW(r0, s + 3);            // input row s+3 -> used next body
    BODY(r1, r2, r0, s + 1);
    LOADROW(r1, s + 4);            // input row s+4
    BODY(r2, r0, r1, s + 2);
    if (nrow == 4) {               // wave-uniform branch (waves 0,1 only)
        LOADROW(r2, s + 5);
        BODY(r0, r1, r2, s + 3);
    }

    // combine: waves 1..7 park partials in LDS, wave 0 reduces + bias + store
    if (wid) {
#pragma unroll
        for (int c = 0; c < NCLS; ++c) part[wid - 1][lane][c] = acc[c];
    }
    __syncthreads();
    if (!wid) {
        float v[NCLS];
#pragma unroll
        for (int c = 0; c < NCLS; ++c) {
            float t = acc[c];
#pragma unroll
            for (int w = 0; w < 7; ++w) t += part[w][lane][c];
            v[c] = t + fc_b[c];
        }
        float* o = out + (size_t)img * NCLS;
#pragma unroll
        for (int q = 0; q < 5; ++q)
            *(float2*)(o + 2 * q) = make_float2(v[2 * q], v[2 * q + 1]);
    }
}

extern "C" void kernel_launch(void* const* d_in, const int* in_sizes, int n_in,
                              void* d_out, int out_size, void* d_ws, size_t ws_size,
                              hipStream_t stream) {
    const float* x      = (const float*)d_in[0];
    const float* conv_w = (const float*)d_in[1];
    const float* fc_w   = (const float*)d_in[2];
    const float* fc_b   = (const float*)d_in[3];
    float* out = (float*)d_out;

    const int nimg   = in_sizes[0] / (IMGW * IMGW);  // 32768
    const int blocks = nimg / 64;                    // 512

    hipLaunchKernelGGL(fused_conv_fc_kernel, dim3(blocks), dim3(512), 0, stream,
                       x, conv_w, fc_w, fc_b, out);
}

// Round 4
// 60.755 us; speedup vs baseline: 1.8346x; 1.8346x over previous
//
#include <hip/hip_runtime.h>

#define IMGW 28
#define OUTW 26
#define FLAT (OUTW * OUTW)
#define NCLS 10
#define PAD  11   // LDS partial stride: 11 is coprime with 32 -> conflict-free

// lane = image; 8 waves per block split one 64-image batch's 26 output rows
// {4,4,3,3,3,3,3,3}. All fc_w indexing is wave-uniform (readfirstlane'd
// offsets) -> s_load on the scalar pipe; VALU does only conv+FC FMAs.
// __launch_bounds__(512,2): CUDA semantics = min 2 BLOCKS/CU = 16 waves/CU
// = 4 waves/SIMD -> VGPR cap 128 (rolling rows 84 + acc 10 + temps fits).
__global__ __launch_bounds__(512, 2) void fused_conv_fc_kernel(
    const float* __restrict__ x,       // [B, 784]
    const float* __restrict__ conv_w,  // [3,3]
    const float* __restrict__ fc_w,    // [10, 676]
    const float* __restrict__ fc_b,    // [10]
    float* __restrict__ out)           // [B, 10]
{
    __shared__ float part[7][64][PAD];   // waves 1..7 partial logits

    const int lane = threadIdx.x & 63;
    const int wid  = __builtin_amdgcn_readfirstlane(threadIdx.x >> 6);
    const int img  = blockIdx.x * 64 + lane;

    const float* ip = x + (size_t)img * (IMGW * IMGW);

    // wave-uniform row assignment: waves 0,1 -> 4 rows; waves 2..7 -> 3 rows
    const int nrow = (wid < 2) ? 4 : 3;
    const int s    = (wid < 2) ? 4 * wid : 8 + 3 * (wid - 2);

    // uniform literal offsets -> scalar loads
    const float cw0 = conv_w[0], cw1 = conv_w[1], cw2 = conv_w[2];
    const float cw3 = conv_w[3], cw4 = conv_w[4], cw5 = conv_w[5];
    const float cw6 = conv_w[6], cw7 = conv_w[7], cw8 = conv_w[8];

    float acc[NCLS];
#pragma unroll
    for (int c = 0; c < NCLS; ++c) acc[c] = 0.f;

    float r0[IMGW], r1[IMGW], r2[IMGW];

#define LOADROW(BUF, RR) do {                                        \
    const float4* _p = (const float4*)(ip + (size_t)(RR) * IMGW);    \
    _Pragma("unroll")                                                \
    for (int q = 0; q < 7; ++q) *(float4*)(&BUF[4 * q]) = _p[q];     \
} while (0)

    // one output row: conv from registers, FC with wave-uniform (scalar)
    // weight loads. woff readfirstlane'd as scalarization insurance.
#define BODY(A, B, C, R) do {                                         \
    const int woff = __builtin_amdgcn_readfirstlane((R) * OUTW);      \
    const float* _w = fc_w + woff;                                    \
    _Pragma("unroll")                                                 \
    for (int cc = 0; cc < OUTW; ++cc) {                               \
        float h = A[cc]     * cw0 + A[cc + 1] * cw1 + A[cc + 2] * cw2 \
                + B[cc]     * cw3 + B[cc + 1] * cw4 + B[cc + 2] * cw5 \
                + C[cc]     * cw6 + C[cc + 1] * cw7 + C[cc + 2] * cw8;\
        h = fmaxf(h, 0.f);                                            \
        _Pragma("unroll")                                             \
        for (int c = 0; c < NCLS; ++c)                                \
            acc[c] = fmaf(h, _w[c * FLAT + cc], acc[c]);              \
    }                                                                 \
} while (0)

    LOADROW(r0, s + 0);
    LOADROW(r1, s + 1);
    LOADROW(r2, s + 2);

    BODY(r0, r1, r2, s + 0);
    LOADROW(r0, s + 3);            // prefetch input row s+3 (max 26)
    BODY(r1, r2, r0, s + 1);
    LOADROW(r1, s + 4);            // prefetch input row s+4 (max 27)
    BODY(r2, r0, r1, s + 2);
    if (nrow == 4) {               // wave-uniform branch (waves 0,1)
        LOADROW(r2, s + 5);        // input row s+5 (max 9)
        BODY(r0, r1, r2, s + 3);
    }

    // combine: waves 1..7 park partials in LDS, wave 0 reduces + bias + store
    if (wid) {
#pragma unroll
        for (int c = 0; c < NCLS; ++c) part[wid - 1][lane][c] = acc[c];
    }
    __syncthreads();
    if (!wid) {
        float v[NCLS];
#pragma unroll
        for (int c = 0; c < NCLS; ++c) {
            float t = acc[c];
#pragma unroll
            for (int w = 0; w < 7; ++w) t += part[w][lane][c];
            v[c] = t + fc_b[c];
        }
        float* o = out + (size_t)img * NCLS;
#pragma unroll
        for (int q = 0; q < 5; ++q)
            *(float2*)(o + 2 * q) = make_float2(v[2 * q], v[2 * q + 1]);
    }
}

extern "C" void kernel_launch(void* const* d_in, const int* in_sizes, int n_in,
                              void* d_out, int out_size, void* d_ws, size_t ws_size,
                              hipStream_t stream) {
    const float* x      = (const float*)d_in[0];
    const float* conv_w = (const float*)d_in[1];
    const float* fc_w   = (const float*)d_in[2];
    const float* fc_b   = (const float*)d_in[3];
    float* out = (float*)d_out;

    const int nimg   = in_sizes[0] / (IMGW * IMGW);  // 32768
    const int blocks = nimg / 64;                    // 512

    hipLaunchKernelGGL(fused_conv_fc_kernel, dim3(blocks), dim3(512), 0, stream,
                       x, conv_w, fc_w, fc_b, out);
}